// Round 1
// baseline (885.696 us; speedup 1.0000x reference)
//
#include <hip/hip_runtime.h>
#include <math.h>

// Problem constants
constexpr int DD    = 512;     // D
constexpr int D2    = 1024;    // 2D
constexpr int NTOK  = 256;     // vocab V (unique tokens = unique pipelines)
constexpr int NSYM  = 512;
constexpr int NCON  = 64;
constexpr int VOCAB = 256;
constexpr int BS_TOT = 32 * 512;   // B*S = 16384
constexpr int NDEPTH = 6;
constexpr int NLOOK  = 3;
constexpr int SPLIT  = 4;          // K-split for gemm64
constexpr float EPSF = 1e-8f;
constexpr float SCALE = 0.044194173824159216f; // 512^-0.5

__device__ inline void fma4(float4& a, const float4& w, float s) {
    a.x += w.x * s; a.y += w.y * s; a.z += w.z * s; a.w += w.w * s;
}

// ---------------- init / histogram ----------------
__global__ void zero_kernel(float* symErr, float* conErr, int* hist) {
    int t = threadIdx.x;
    symErr[t] = 0.f; conErr[t] = 0.f; hist[t] = 0;
}

__global__ void hist_kernel(const int* __restrict__ x, int* __restrict__ hist) {
    int i = blockIdx.x * 256 + threadIdx.x;
    atomicAdd(&hist[x[i]], 1);
}

// ---------------- transpose with output stride: out[c*ldo + r] = in[r*C + c] ----------------
// grid (C/32, R/32), block (32,8)
__global__ void transposeS_kernel(const float* __restrict__ in, float* __restrict__ out,
                                  int R, int C, int ldo) {
    __shared__ float t[32][33];
    int c0 = blockIdx.x * 32, r0 = blockIdx.y * 32;
    int x = threadIdx.x, y = threadIdx.y;
#pragma unroll
    for (int i = 0; i < 32; i += 8)
        t[y + i][x] = in[(size_t)(r0 + y + i) * C + c0 + x];
    __syncthreads();
#pragma unroll
    for (int i = 0; i < 32; i += 8)
        out[(size_t)(c0 + y + i) * ldo + r0 + x] = t[x][y + i];
}

// ---------------- build combined cell weight CW[1024][1024] ----------------
// CW[k][j]=Wr[j][k]; CW[k][512+j]=Wi[j][k]; CW[512+k][j]=-Wi[j][k]; CW[512+k][512+j]=Wr[j][k]
// grid (16,16) over (j-tile, k-tile), block (32,8)
__global__ void buildcw_kernel(const float* __restrict__ Wr, const float* __restrict__ Wi,
                               float* __restrict__ CW) {
    __shared__ float tr[32][33], ti[32][33];
    int j0 = blockIdx.x * 32, k0 = blockIdx.y * 32;
    int x = threadIdx.x, y = threadIdx.y;
#pragma unroll
    for (int i = 0; i < 32; i += 8) {
        tr[y + i][x] = Wr[(size_t)(j0 + y + i) * DD + k0 + x];
        ti[y + i][x] = Wi[(size_t)(j0 + y + i) * DD + k0 + x];
    }
    __syncthreads();
#pragma unroll
    for (int i = 0; i < 32; i += 8) {
        float vr = tr[x][y + i];    // Wr[j0+x][k0+y+i]
        float vi = ti[x][y + i];
        int k = k0 + y + i, j = j0 + x;
        CW[(size_t)k * D2 + j]                    = vr;
        CW[(size_t)k * D2 + DD + j]               = vi;
        CW[(size_t)(DD + k) * D2 + j]             = -vi;
        CW[(size_t)(DD + k) * D2 + DD + j]        = vr;
    }
}

// ---------------- embedding ----------------
__global__ void embed_kernel(const float* __restrict__ mag, const float* __restrict__ phase,
                             float* __restrict__ dst) {
    int v = blockIdx.x, j = threadIdx.x;          // block 512
    float r = mag[v * DD + j], t = phase[v * DD + j];
    dst[v * D2 + j]      = r * cosf(t);
    dst[v * D2 + DD + j] = r * sinf(t);
}

// ---------------- sym code norms ----------------
__global__ void symnorm_kernel(const float* __restrict__ sym, float* __restrict__ snorm) {
    int c = blockIdx.x, tid = threadIdx.x;        // block 256
    const float4* r = (const float4*)(sym + (size_t)c * D2);
    float4 v = r[tid];
    float p = v.x*v.x + v.y*v.y + v.z*v.z + v.w*v.w;
    __shared__ float red[256];
    red[tid] = p; __syncthreads();
    for (int off = 128; off > 0; off >>= 1) {
        if (tid < off) red[tid] += red[tid + off];
        __syncthreads();
    }
    if (tid == 0) snorm[c] = red[0];
}

// ---------------- tiled GEMM: P[s][t][j] = sum_{k in slice s} X[t][k]*WT[k][j] ----------------
// X: [256][1024] (t-major). WT: [1024][N] (k-major). P: [SPLIT][256][N].
// grid (N/64, 4, SPLIT), block 256. Tile 64j x 64t, thread 4x4. No bias (consumers add it).
__global__ __launch_bounds__(256) void gemm64_kernel(const float* __restrict__ WT,
                                                     const float* __restrict__ X,
                                                     float* __restrict__ P,
                                                     int N) {
    constexpr int KB = D2 / SPLIT;     // 256 k per block
    constexpr int LDT = 68;            // padded LDS row stride
    __shared__ float sX[32 * LDT];     // [k][t]
    __shared__ float sW[32 * LDT];     // [k][j]

    int tid = threadIdx.x;
    int j0 = blockIdx.x * 64;
    int t0 = blockIdx.y * 64;
    int s  = blockIdx.z;
    int k0 = s * KB;

    int jq = tid & 15;        // 16 j-groups of 4
    int tq = tid >> 4;        // 16 t-groups of 4

    float4 acc0 = {0,0,0,0}, acc1 = {0,0,0,0}, acc2 = {0,0,0,0}, acc3 = {0,0,0,0};

    for (int kc = 0; kc < KB / 32; ++kc) {
        int kbase = k0 + kc * 32;
        __syncthreads();
        // stage X tile (64t x 32k, transposed to [k][t]) and W tile (32k x 64j)
#pragma unroll
        for (int b = 0; b < 2; ++b) {
            int f = tid * 2 + b;
            // X: f in [0,512): t = f>>3 (64 tokens), kq = f&7 (8 float4 along k)
            int t = f >> 3, kq = f & 7;
            float4 v = *(const float4*)&X[(size_t)(t0 + t) * D2 + kbase + kq * 4];
            sX[(kq * 4 + 0) * LDT + t] = v.x;
            sX[(kq * 4 + 1) * LDT + t] = v.y;
            sX[(kq * 4 + 2) * LDT + t] = v.z;
            sX[(kq * 4 + 3) * LDT + t] = v.w;
            // W: k = f>>4 (32 rows), j4 = f&15 (16 float4 along j)
            int kw = f >> 4, j4 = f & 15;
            float4 w = *(const float4*)&WT[(size_t)(kbase + kw) * N + j0 + j4 * 4];
            *(float4*)&sW[kw * LDT + j4 * 4] = w;
        }
        __syncthreads();
#pragma unroll 8
        for (int k = 0; k < 32; ++k) {
            float4 xa = *(const float4*)&sX[k * LDT + tq * 4];
            float4 wb = *(const float4*)&sW[k * LDT + jq * 4];
            fma4(acc0, wb, xa.x);
            fma4(acc1, wb, xa.y);
            fma4(acc2, wb, xa.z);
            fma4(acc3, wb, xa.w);
        }
    }
    size_t base = ((size_t)s * NTOK + (t0 + tq * 4)) * N + j0 + jq * 4;
    *(float4*)&P[base]         = acc0;
    *(float4*)&P[base + N]     = acc1;
    *(float4*)&P[base + 2*N]   = acc2;
    *(float4*)&P[base + 3*N]   = acc3;
}

// ---------------- cell epilogue: sum partials, complex saturating norm + tanh ----------------
// grid (2, 256): j = bx*256+tid in [0,512), t = by
__global__ __launch_bounds__(256) void cellepi_kernel(const float* __restrict__ P,
                                                      float* __restrict__ z) {
    int j = blockIdx.x * 256 + threadIdx.x;
    int t = blockIdx.y;
    size_t idx = (size_t)t * D2 + j;
    float lr = 0.f, li = 0.f;
#pragma unroll
    for (int s = 0; s < SPLIT; ++s) {
        lr += P[((size_t)s * NTOK + t) * D2 + j];
        li += P[((size_t)s * NTOK + t) * D2 + DD + j];
    }
    float m = sqrtf(lr * lr + li * li + EPSF);
    float inv = 1.0f / (1.0f + m);
    z[idx]      = tanhf(lr * inv);
    z[idx + DD] = tanhf(li * inv);
}

// ---------------- KV combine: Kmem/Vmem slot = sum partials + bias ----------------
// grid (6, 256): e = bx*256+tid in [0,1536), t = by
__global__ __launch_bounds__(256) void kvcomb_kernel(const float* __restrict__ P,
                                                     const float* __restrict__ kb,
                                                     const float* __restrict__ vb,
                                                     float* __restrict__ Kslot,
                                                     float* __restrict__ Vslot) {
    int e = blockIdx.x * 256 + threadIdx.x;
    int t = blockIdx.y;
    float v = 0.f;
#pragma unroll
    for (int s = 0; s < SPLIT; ++s)
        v += P[((size_t)s * NTOK + t) * 1536 + e];
    if (e < DD) Kslot[(size_t)t * DD + e]        = v + kb[e];
    else        Vslot[(size_t)t * D2 + (e - DD)] = v + vb[e - DD];
}

// ---------------- dec combine: rows = sum partials + dec_b ----------------
// grid 256, block 256: t = bid, j = tid
__global__ void deccomb_kernel(const float* __restrict__ P, const float* __restrict__ db,
                               float* __restrict__ rows) {
    int t = blockIdx.x, j = threadIdx.x;
    float v = 0.f;
#pragma unroll
    for (int s = 0; s < SPLIT; ++s)
        v += P[((size_t)s * NTOK + t) * VOCAB + j];
    rows[(size_t)t * VOCAB + j] = v + db[j];
}

// ---------------- attend: scores, softmax, ctx update (Q from partials + qb) ----------------
// grid 256 (token), block 256. M = number of memory entries.
__global__ __launch_bounds__(256) void attend_kernel(float* __restrict__ z,
                                                     const float* __restrict__ QP,
                                                     const float* __restrict__ qb,
                                                     const float* __restrict__ Kmem,
                                                     const float* __restrict__ Vmem,
                                                     const float* __restrict__ conf,
                                                     int M) {
    int v = blockIdx.x, tid = threadIdx.x;
    __shared__ float red[256];
    __shared__ float s_sc[8];
    float q0 = 0.f, q1 = 0.f;
#pragma unroll
    for (int s = 0; s < SPLIT; ++s) {
        q0 += QP[((size_t)s * NTOK + v) * DD + tid];
        q1 += QP[((size_t)s * NTOK + v) * DD + 256 + tid];
    }
    q0 += qb[tid];
    q1 += qb[256 + tid];
    for (int m = 0; m < M; ++m) {
        const float* K = Kmem + (size_t)m * NTOK * DD + (size_t)v * DD;
        red[tid] = q0 * K[tid] + q1 * K[256 + tid];
        __syncthreads();
        for (int off = 128; off > 0; off >>= 1) {
            if (tid < off) red[tid] += red[tid + off];
            __syncthreads();
        }
        if (tid == 0) s_sc[m] = red[0] * SCALE * conf[v];
        __syncthreads();
    }
    if (tid == 0) {
        float mx = s_sc[0];
        for (int m = 1; m < M; ++m) mx = fmaxf(mx, s_sc[m]);
        float w[5], sum = 0.f;
        for (int m = 0; m < M; ++m) { w[m] = expf(s_sc[m] - mx); sum += w[m]; }
        for (int m = 0; m < M; ++m) s_sc[m] = w[m] / sum;
    }
    __syncthreads();
#pragma unroll
    for (int r = 0; r < 4; ++r) {
        int e = r * 256 + tid;
        float ctx = 0.f;
        for (int m = 0; m < M; ++m)
            ctx += s_sc[m] * Vmem[(size_t)m * NTOK * D2 + (size_t)v * D2 + e];
        z[(size_t)v * D2 + e] += 0.1f * ctx;
    }
}

// ---------------- finish: argmin, conf, straight-through update, losses, con quantize ----
// grid 256 (1 token/block), block 512. dot from symP partials.
__global__ __launch_bounds__(512) void finish_kernel(float* __restrict__ z,
                                                     const float* __restrict__ sym,
                                                     const float* __restrict__ snorm,
                                                     const float* __restrict__ con,
                                                     const float* __restrict__ conT,
                                                     const float* __restrict__ symP,
                                                     float* __restrict__ conf,
                                                     float* __restrict__ symErr,
                                                     float* __restrict__ conErr) {
    int t0 = blockIdx.x;
    int tid = threadIdx.x;
    __shared__ __align__(16) float s_z[D2];
    __shared__ float s_red[512];
    __shared__ int   s_idx[512];
    __shared__ float s_res[4];
    __shared__ int   s_si[1];
    __shared__ float s_pd[256], s_pc[256];

    if (tid < 256) ((float4*)s_z)[tid] = ((const float4*)(z + (size_t)t0 * D2))[tid];
    __syncthreads();

    // ||z||^2 (pre-update)
    {
        float a = s_z[tid], b = s_z[512 + tid];
        s_red[tid] = a * a + b * b;
        __syncthreads();
        for (int off = 256; off > 0; off >>= 1) {
            if (tid < off) s_red[tid] += s_red[tid + off];
            __syncthreads();
        }
        if (tid == 0) s_res[0] = s_red[0];
        __syncthreads();
    }

    // d = (znorm + cn) - 2*dot ; argmin (first-min tie-break)
    {
        float dot = 0.f;
#pragma unroll
        for (int s = 0; s < SPLIT; ++s)
            dot += symP[((size_t)s * NTOK + t0) * NSYM + tid];
        float d = (s_res[0] + snorm[tid]) - 2.f * dot;
        s_red[tid] = d; s_idx[tid] = tid;
        __syncthreads();
        for (int off = 256; off > 0; off >>= 1) {
            if (tid < off) {
                float o = s_red[tid + off]; int oi = s_idx[tid + off];
                if (o < s_red[tid] || (o == s_red[tid] && oi < s_idx[tid])) {
                    s_red[tid] = o; s_idx[tid] = oi;
                }
            }
            __syncthreads();
        }
        if (tid == 0) { s_res[1] = s_red[0]; s_si[0] = s_idx[0]; }
        __syncthreads();
    }

    // conf, straight-through update, symErr (direct form)
    {
        int si = s_si[0];
        if (tid == 0) conf[t0] = 1.0f / (1.0f + s_res[1]);
        const float* crow = sym + (size_t)si * D2;
        float errp = 0.f;
#pragma unroll
        for (int r = 0; r < 2; ++r) {
            int e = r * 512 + tid;
            float zf = s_z[e];
            float diff = crow[e] - zf;
            errp += diff * diff;
            float zn = zf + diff;      // zs = z + (c - z), exact two-op fp
            s_z[e] = zn;
            z[(size_t)t0 * D2 + e] = zn;
        }
        s_red[tid] = errp;
        __syncthreads();
        for (int off = 256; off > 0; off >>= 1) {
            if (tid < off) s_red[tid] += s_red[tid + off];
            __syncthreads();
        }
        if (tid == 0) symErr[t0] += s_red[0];
        __syncthreads();
    }

    // ||zs||^2
    {
        float a = s_z[tid], b = s_z[512 + tid];
        s_red[tid] = a * a + b * b;
        __syncthreads();
        for (int off = 256; off > 0; off >>= 1) {
            if (tid < off) s_red[tid] += s_red[tid + off];
            __syncthreads();
        }
        if (tid == 0) s_res[2] = s_red[0];
        __syncthreads();
    }

    // con partial dots, split-K over 4 waves (coalesced conT reads)
    if (tid < 256) {
        int c = tid & 63, sl = tid >> 6;
        float pd = 0.f, pc = 0.f;
        int k0 = sl * 256;
#pragma unroll 4
        for (int k = k0; k < k0 + 256; ++k) {
            float w = conT[(size_t)k * NCON + c];
            pd += w * s_z[k];
            pc += w * w;
        }
        s_pd[tid] = pd; s_pc[tid] = pc;
    }
    __syncthreads();
    if (tid < 64) {
        float dot = ((s_pd[tid] + s_pd[64 + tid]) + s_pd[128 + tid]) + s_pd[192 + tid];
        float cn2 = ((s_pc[tid] + s_pc[64 + tid]) + s_pc[128 + tid]) + s_pc[192 + tid];
        s_red[tid] = (s_res[2] + cn2) - 2.f * dot;
        s_idx[tid] = tid;
    }
    __syncthreads();
    for (int off = 32; off > 0; off >>= 1) {
        if (tid < off) {
            float o = s_red[tid + off]; int oi = s_idx[tid + off];
            if (o < s_red[tid] || (o == s_red[tid] && oi < s_idx[tid])) {
                s_red[tid] = o; s_idx[tid] = oi;
            }
        }
        __syncthreads();
    }
    int ci0 = s_idx[0];
    __syncthreads();

    // conErr (direct form vs zs)
    {
        const float* crow = con + (size_t)ci0 * D2;
        float p = 0.f;
#pragma unroll
        for (int r = 0; r < 2; ++r) {
            int e = r * 512 + tid;
            float diff = crow[e] - s_z[e];
            p += diff * diff;
        }
        s_red[tid] = p;
        __syncthreads();
        for (int off = 256; off > 0; off >>= 1) {
            if (tid < off) s_red[tid] += s_red[tid + off];
            __syncthreads();
        }
        if (tid == 0) conErr[t0] += s_red[0];
        __syncthreads();
    }
}

// ---------------- scatter: out[pos] = rows[x[pos]] ----------------
__global__ __launch_bounds__(256) void scatter_kernel(const int* __restrict__ x,
                                                      const float* __restrict__ rows,
                                                      float* __restrict__ out) {
    int tid = threadIdx.x;
    int pos = blockIdx.x * 4 + (tid >> 6);
    int lane = tid & 63;
    int v = x[pos];
    const float4* r = (const float4*)(rows + (size_t)v * VOCAB);
    ((float4*)(out + (size_t)pos * VOCAB))[lane] = r[lane];
}

// ---------------- losses ----------------
__global__ void loss_kernel(const int* __restrict__ hist,
                            const float* __restrict__ symErr,
                            const float* __restrict__ conErr,
                            float* __restrict__ out) {
    int tid = threadIdx.x;   // 256
    __shared__ double rs[256], rc[256];
    rs[tid] = (double)hist[tid] * (double)symErr[tid];
    rc[tid] = (double)hist[tid] * (double)conErr[tid];
    __syncthreads();
    for (int off = 128; off > 0; off >>= 1) {
        if (tid < off) { rs[tid] += rs[tid + off]; rc[tid] += rc[tid + off]; }
        __syncthreads();
    }
    if (tid == 0) {
        const double denom = (double)BS_TOT * (double)D2;   // 16777216
        out[(size_t)BS_TOT * VOCAB]     = (float)(1.25 * rs[0] / denom);
        out[(size_t)BS_TOT * VOCAB + 1] = (float)(1.25 * rc[0] / denom);
    }
}

// ---------------- host ----------------
extern "C" void kernel_launch(void* const* d_in, const int* in_sizes, int n_in,
                              void* d_out, int out_size, void* d_ws, size_t ws_size,
                              hipStream_t stream) {
    const int*   x     = (const int*)  d_in[0];
    const float* mag   = (const float*)d_in[1];
    const float* phase = (const float*)d_in[2];
    const float* Wr    = (const float*)d_in[3];
    const float* Wi    = (const float*)d_in[4];
    const float* qw    = (const float*)d_in[5];
    const float* qb    = (const float*)d_in[6];
    const float* kw    = (const float*)d_in[7];
    const float* kb    = (const float*)d_in[8];
    const float* vw    = (const float*)d_in[9];
    const float* vb    = (const float*)d_in[10];
    const float* dec_w = (const float*)d_in[11];
    const float* dec_b = (const float*)d_in[12];
    const float* sym   = (const float*)d_in[13];
    const float* con   = (const float*)d_in[14];
    float* out = (float*)d_out;

    // workspace layout (floats); total ~44 MB
    float* ws     = (float*)d_ws;
    float* bufA   = ws;                          // 256*1024
    float* bufB   = bufA + NTOK * D2;            // 256*1024
    float* Kmem   = bufB + NTOK * D2;            // 6*256*512
    float* Vmem   = Kmem + NDEPTH * NTOK * DD;   // 6*256*1024
    float* rows   = Vmem + NDEPTH * NTOK * D2;   // 256*256
    float* CW     = rows + NTOK * VOCAB;         // 1024*1024
    float* qwT    = CW + D2 * D2;                // 1024*512
    float* KVT    = qwT + D2 * DD;               // 1024*1536
    float* symT   = KVT + D2 * 1536;             // 1024*512
    float* decT   = symT + D2 * NSYM;            // 1024*256
    float* conT   = decT + D2 * VOCAB;           // 1024*64
    float* cellP  = conT + D2 * NCON;            // 4*256*1024
    float* QP     = cellP + SPLIT * NTOK * D2;   // 4*256*512
    float* symP   = QP + SPLIT * NTOK * DD;      // 4*256*512
    float* kvP    = symP + SPLIT * NTOK * NSYM;  // 4*256*1536
    float* decP   = kvP + SPLIT * NTOK * 1536;   // 4*256*256
    float* snorm  = decP + SPLIT * NTOK * VOCAB; // 512
    float* conf   = snorm + NSYM;                // 256
    float* symErr = conf + NTOK;                 // 256
    float* conErr = symErr + NTOK;               // 256
    int*   hist   = (int*)(conErr + NTOK);       // 256

    dim3 tb(32, 8);
    buildcw_kernel<<<dim3(16, 16), tb, 0, stream>>>(Wr, Wi, CW);
    transposeS_kernel<<<dim3(32, 16), tb, 0, stream>>>(qw,    qwT,       DD,    D2, DD);
    transposeS_kernel<<<dim3(32, 16), tb, 0, stream>>>(kw,    KVT,       DD,    D2, 1536);
    transposeS_kernel<<<dim3(32, 32), tb, 0, stream>>>(vw,    KVT + DD,  D2,    D2, 1536);
    transposeS_kernel<<<dim3(32, 16), tb, 0, stream>>>(sym,   symT,      NSYM,  D2, NSYM);
    transposeS_kernel<<<dim3(32,  8), tb, 0, stream>>>(dec_w, decT,      VOCAB, D2, VOCAB);
    transposeS_kernel<<<dim3(32,  2), tb, 0, stream>>>(con,   conT,      NCON,  D2, NCON);

    zero_kernel<<<1, 256, 0, stream>>>(symErr, conErr, hist);
    hist_kernel<<<BS_TOT / 256, 256, 0, stream>>>(x, hist);
    symnorm_kernel<<<NSYM, 256, 0, stream>>>(sym, snorm);
    embed_kernel<<<NTOK, 512, 0, stream>>>(mag, phase, bufA);

    float* cur = bufA;
    float* oth = bufB;
    for (int d = 0; d < NDEPTH; ++d) {
        gemm64_kernel<<<dim3(16, 4, SPLIT), 256, 0, stream>>>(CW, cur, cellP, D2);
        cellepi_kernel<<<dim3(2, 256), 256, 0, stream>>>(cellP, oth);
        { float* t = cur; cur = oth; oth = t; }
        if (d > 0) {
            gemm64_kernel<<<dim3(8, 4, SPLIT), 256, 0, stream>>>(qwT, cur, QP, DD);
            attend_kernel<<<NTOK, 256, 0, stream>>>(cur, QP, qb, Kmem, Vmem, conf, d);
        }
        gemm64_kernel<<<dim3(8, 4, SPLIT), 256, 0, stream>>>(symT, cur, symP, NSYM);
        finish_kernel<<<NTOK, 512, 0, stream>>>(cur, sym, snorm, con, conT, symP,
                                                conf, symErr, conErr);
        gemm64_kernel<<<dim3(24, 4, SPLIT), 256, 0, stream>>>(KVT, cur, kvP, 1536);
        kvcomb_kernel<<<dim3(6, 256), 256, 0, stream>>>(kvP, kb, vb,
                                                        Kmem + (size_t)d * NTOK * DD,
                                                        Vmem + (size_t)d * NTOK * D2);
    }
    for (int l = 0; l < NLOOK; ++l) {
        gemm64_kernel<<<dim3(16, 4, SPLIT), 256, 0, stream>>>(CW, cur, cellP, D2);
        cellepi_kernel<<<dim3(2, 256), 256, 0, stream>>>(cellP, oth);
        { float* t = cur; cur = oth; oth = t; }
    }
    gemm64_kernel<<<dim3(4, 4, SPLIT), 256, 0, stream>>>(decT, cur, decP, VOCAB);
    deccomb_kernel<<<256, 256, 0, stream>>>(decP, dec_b, rows);
    scatter_kernel<<<BS_TOT / 4, 256, 0, stream>>>(x, rows, out);
    loss_kernel<<<1, 256, 0, stream>>>(hist, symErr, conErr, out);
}

// Round 2
// 630.926 us; speedup vs baseline: 1.4038x; 1.4038x over previous
//
#include <hip/hip_runtime.h>
#include <math.h>

// Problem constants
constexpr int DD    = 512;     // D
constexpr int D2    = 1024;    // 2D
constexpr int NTOK  = 256;     // vocab V (unique tokens = unique pipelines)
constexpr int NSYM  = 512;
constexpr int NCON  = 64;
constexpr int VOCAB = 256;
constexpr int BS_TOT = 32 * 512;   // B*S = 16384
constexpr int NDEPTH = 6;
constexpr int NLOOK  = 3;
constexpr float EPSF = 1e-8f;
constexpr float SCALE = 0.044194173824159216f; // 512^-0.5

__device__ inline void fma4(float4& a, const float4& w, float s) {
    a.x += w.x * s; a.y += w.y * s; a.z += w.z * s; a.w += w.w * s;
}

__device__ inline float wave_sum(float x) {
#pragma unroll
    for (int off = 32; off; off >>= 1) x += __shfl_xor(x, off, 64);
    return x;
}

__device__ inline void wave_argmin(float& d, int& i) {
#pragma unroll
    for (int off = 32; off; off >>= 1) {
        float od = __shfl_xor(d, off, 64);
        int   oi = __shfl_xor(i, off, 64);
        if (od < d || (od == d && oi < i)) { d = od; i = oi; }
    }
}

// ---------------- batched setup: 6 transposes + zero-init ----------------
// All sources have C = 1024 columns. block (32,8).
__global__ void tbatch_kernel(const float* __restrict__ qw, const float* __restrict__ kw,
                              const float* __restrict__ vw, const float* __restrict__ sym,
                              const float* __restrict__ dec_w, const float* __restrict__ con,
                              float* __restrict__ qwT, float* __restrict__ KVT,
                              float* __restrict__ symT, float* __restrict__ decT,
                              float* __restrict__ conT,
                              float* __restrict__ symErr, float* __restrict__ conErr,
                              int* __restrict__ hist) {
    int b = blockIdx.x;
    const float* in; float* out; int ldo;
    if      (b < 512)  {           in = qw;    out = qwT;      ldo = DD;    }
    else if (b < 1024) { b -= 512; in = kw;    out = KVT;      ldo = 1536;  }
    else if (b < 2048) { b -= 1024; in = vw;   out = KVT + DD; ldo = 1536;  }
    else if (b < 2560) { b -= 2048; in = sym;  out = symT;     ldo = NSYM;  }
    else if (b < 2816) { b -= 2560; in = dec_w; out = decT;    ldo = VOCAB; }
    else if (b < 2880) { b -= 2816; in = con;  out = conT;     ldo = NCON;  }
    else {
        int t = threadIdx.y * 32 + threadIdx.x;  // 256 threads
        symErr[t] = 0.f; conErr[t] = 0.f; hist[t] = 0;
        return;
    }
    __shared__ float t[32][33];
    int bx = b & 31, by = b >> 5;
    int c0 = bx * 32, r0 = by * 32;
    int x = threadIdx.x, y = threadIdx.y;
#pragma unroll
    for (int i = 0; i < 32; i += 8)
        t[y + i][x] = in[(size_t)(r0 + y + i) * D2 + c0 + x];
    __syncthreads();
#pragma unroll
    for (int i = 0; i < 32; i += 8)
        out[(size_t)(c0 + y + i) * ldo + r0 + x] = t[x][y + i];
}

__global__ void hist_kernel(const int* __restrict__ x, int* __restrict__ hist) {
    int i = blockIdx.x * 256 + threadIdx.x;
    atomicAdd(&hist[x[i]], 1);
}

// ---------------- build combined cell weight CW[1024][1024] ----------------
__global__ void buildcw_kernel(const float* __restrict__ Wr, const float* __restrict__ Wi,
                               float* __restrict__ CW) {
    __shared__ float tr[32][33], ti[32][33];
    int j0 = blockIdx.x * 32, k0 = blockIdx.y * 32;
    int x = threadIdx.x, y = threadIdx.y;
#pragma unroll
    for (int i = 0; i < 32; i += 8) {
        tr[y + i][x] = Wr[(size_t)(j0 + y + i) * DD + k0 + x];
        ti[y + i][x] = Wi[(size_t)(j0 + y + i) * DD + k0 + x];
    }
    __syncthreads();
#pragma unroll
    for (int i = 0; i < 32; i += 8) {
        float vr = tr[x][y + i];    // Wr[j0+x][k0+y+i]
        float vi = ti[x][y + i];
        int k = k0 + y + i, j = j0 + x;
        CW[(size_t)k * D2 + j]                    = vr;
        CW[(size_t)k * D2 + DD + j]               = vi;
        CW[(size_t)(DD + k) * D2 + j]             = -vi;
        CW[(size_t)(DD + k) * D2 + DD + j]        = vr;
    }
}

// ---------------- embed (blocks 0..255) + sym norms (blocks 256..767), block 512 ----------------
__global__ __launch_bounds__(512) void symembed_kernel(const float* __restrict__ mag,
                                                       const float* __restrict__ phase,
                                                       const float* __restrict__ sym,
                                                       float* __restrict__ dst,
                                                       float* __restrict__ snorm) {
    int bid = blockIdx.x, tid = threadIdx.x;
    if (bid < NTOK) {
        int v = bid, j = tid;
        float r = mag[v * DD + j], t = phase[v * DD + j];
        dst[(size_t)v * D2 + j]      = r * cosf(t);
        dst[(size_t)v * D2 + DD + j] = r * sinf(t);
        return;
    }
    int c = bid - NTOK;
    float2 vv = ((const float2*)(sym + (size_t)c * D2))[tid];
    float p = vv.x * vv.x + vv.y * vv.y;
    p = wave_sum(p);
    __shared__ float s_w[8];
    int lane = tid & 63, w = tid >> 6;
    if (lane == 0) s_w[w] = p;
    __syncthreads();
    if (tid == 0) {
        float s = 0.f;
#pragma unroll
        for (int k = 0; k < 8; ++k) s += s_w[k];
        snorm[c] = s;
    }
}

// ---------------- tiled GEMM, double-buffered LDS, templated K-slice ----------------
// X: [256][1024]. WT: [1024][N]. P: [z][256][N]. grid (N/64, 4, D2/KB), block 256.
template<int KB>
__global__ __launch_bounds__(256) void gemmT_kernel(const float* __restrict__ WT,
                                                    const float* __restrict__ X,
                                                    float* __restrict__ P,
                                                    int N) {
    constexpr int NC  = KB / 32;
    constexpr int LDT = 68;
    __shared__ __align__(16) float sX[2][32 * LDT];
    __shared__ __align__(16) float sW[2][32 * LDT];

    int tid = threadIdx.x;
    int j0 = blockIdx.x * 64;
    int t0 = blockIdx.y * 64;
    int s  = blockIdx.z;
    int k0 = s * KB;

    int jq = tid & 15;
    int tq = tid >> 4;

    // staging decomposition (two 16B elements per thread)
    int f0 = tid * 2, f1 = tid * 2 + 1;
    int tA0 = f0 >> 3, kqA0 = f0 & 7;
    int tA1 = f1 >> 3, kqA1 = f1 & 7;
    int kwB0 = f0 >> 4, jB0 = f0 & 15;
    int kwB1 = f1 >> 4, jB1 = f1 & 15;

    float4 vx0, vx1, vw0, vw1;

#define GLOAD(kbase) do { \
        vx0 = *(const float4*)&X[(size_t)(t0 + tA0) * D2 + (kbase) + kqA0 * 4]; \
        vx1 = *(const float4*)&X[(size_t)(t0 + tA1) * D2 + (kbase) + kqA1 * 4]; \
        vw0 = *(const float4*)&WT[(size_t)((kbase) + kwB0) * N + j0 + jB0 * 4]; \
        vw1 = *(const float4*)&WT[(size_t)((kbase) + kwB1) * N + j0 + jB1 * 4]; \
    } while (0)

#define LSTORE(bufi) do { \
        sX[bufi][(kqA0 * 4 + 0) * LDT + tA0] = vx0.x; \
        sX[bufi][(kqA0 * 4 + 1) * LDT + tA0] = vx0.y; \
        sX[bufi][(kqA0 * 4 + 2) * LDT + tA0] = vx0.z; \
        sX[bufi][(kqA0 * 4 + 3) * LDT + tA0] = vx0.w; \
        sX[bufi][(kqA1 * 4 + 0) * LDT + tA1] = vx1.x; \
        sX[bufi][(kqA1 * 4 + 1) * LDT + tA1] = vx1.y; \
        sX[bufi][(kqA1 * 4 + 2) * LDT + tA1] = vx1.z; \
        sX[bufi][(kqA1 * 4 + 3) * LDT + tA1] = vx1.w; \
        *(float4*)&sW[bufi][kwB0 * LDT + jB0 * 4] = vw0; \
        *(float4*)&sW[bufi][kwB1 * LDT + jB1 * 4] = vw1; \
    } while (0)

    float4 acc0 = {0,0,0,0}, acc1 = {0,0,0,0}, acc2 = {0,0,0,0}, acc3 = {0,0,0,0};

    GLOAD(k0);
    LSTORE(0);
    __syncthreads();

    for (int kc = 0; kc < NC; ++kc) {
        if (kc + 1 < NC) GLOAD(k0 + (kc + 1) * 32);
        int buf = kc & 1;
#pragma unroll 8
        for (int k = 0; k < 32; ++k) {
            float4 xa = *(const float4*)&sX[buf][k * LDT + tq * 4];
            float4 wb = *(const float4*)&sW[buf][k * LDT + jq * 4];
            fma4(acc0, wb, xa.x);
            fma4(acc1, wb, xa.y);
            fma4(acc2, wb, xa.z);
            fma4(acc3, wb, xa.w);
        }
        if (kc + 1 < NC) LSTORE((kc + 1) & 1);
        __syncthreads();
    }
#undef GLOAD
#undef LSTORE

    size_t base = ((size_t)s * NTOK + (t0 + tq * 4)) * N + j0 + jq * 4;
    *(float4*)&P[base]         = acc0;
    *(float4*)&P[base + N]     = acc1;
    *(float4*)&P[base + 2*N]   = acc2;
    *(float4*)&P[base + 3*N]   = acc3;
}

// ---------------- merged cell epilogue (bx<2) + prev-iter KV combine (bx>=2) ----------------
// grid (8, 256), block 256.
__global__ __launch_bounds__(256) void epikv_kernel(const float* __restrict__ cellP,
                                                    float* __restrict__ z,
                                                    const float* __restrict__ kvP,
                                                    const float* __restrict__ kb,
                                                    const float* __restrict__ vb,
                                                    float* __restrict__ Kslot,
                                                    float* __restrict__ Vslot,
                                                    int doKV) {
    int bx = blockIdx.x, t = blockIdx.y, tid = threadIdx.x;
    if (bx < 2) {
        int j = bx * 256 + tid;
        float lr = 0.f, li = 0.f;
#pragma unroll
        for (int s = 0; s < 8; ++s) {
            lr += cellP[((size_t)s * NTOK + t) * D2 + j];
            li += cellP[((size_t)s * NTOK + t) * D2 + DD + j];
        }
        float m = sqrtf(lr * lr + li * li + EPSF);
        float inv = 1.0f / (1.0f + m);
        z[(size_t)t * D2 + j]      = tanhf(lr * inv);
        z[(size_t)t * D2 + DD + j] = tanhf(li * inv);
    } else if (doKV) {
        int e = (bx - 2) * 256 + tid;
        float v = 0.f;
#pragma unroll
        for (int s = 0; s < 4; ++s)
            v += kvP[((size_t)s * NTOK + t) * 1536 + e];
        if (e < DD) Kslot[(size_t)t * DD + e]        = v + kb[e];
        else        Vslot[(size_t)t * D2 + (e - DD)] = v + vb[e - DD];
    }
}

// ---------------- dec combine: rows = sum of 16 partials + dec_b ----------------
__global__ void deccomb_kernel(const float* __restrict__ P, const float* __restrict__ db,
                               float* __restrict__ rows) {
    int t = blockIdx.x, j = threadIdx.x;
    float v = 0.f;
#pragma unroll
    for (int s = 0; s < 16; ++s)
        v += P[((size_t)s * NTOK + t) * VOCAB + j];
    rows[(size_t)t * VOCAB + j] = v + db[j];
}

// ---------------- attend: wave-shuffle reduce, softmax, ctx ----------------
// grid 256 (token), block 256. M <= 5.
__global__ __launch_bounds__(256) void attend_kernel(float* __restrict__ z,
                                                     const float* __restrict__ QP,
                                                     const float* __restrict__ qb,
                                                     const float* __restrict__ Kmem,
                                                     const float* __restrict__ Vmem,
                                                     const float* __restrict__ conf,
                                                     int M) {
    int v = blockIdx.x, tid = threadIdx.x;
    int lane = tid & 63, w = tid >> 6;
    __shared__ float s_part[4][5];

    float q0 = 0.f, q1 = 0.f;
#pragma unroll
    for (int s = 0; s < 8; ++s) {
        q0 += QP[((size_t)s * NTOK + v) * DD + tid];
        q1 += QP[((size_t)s * NTOK + v) * DD + 256 + tid];
    }
    q0 += qb[tid];
    q1 += qb[256 + tid];

    float sc[5];
#pragma unroll
    for (int m = 0; m < 5; ++m) {
        if (m < M) {
            const float* K = Kmem + (size_t)m * NTOK * DD + (size_t)v * DD;
            sc[m] = q0 * K[tid] + q1 * K[256 + tid];
        } else sc[m] = 0.f;
    }
#pragma unroll
    for (int m = 0; m < 5; ++m) {
        if (m < M) {
            float x = wave_sum(sc[m]);
            if (lane == 0) s_part[w][m] = x;
        }
    }
    __syncthreads();

    float cf = conf[v];
    float scf[5];
    float mx = -1e30f;
#pragma unroll
    for (int m = 0; m < 5; ++m) {
        if (m < M) {
            float t = (s_part[0][m] + s_part[1][m] + s_part[2][m] + s_part[3][m]) * SCALE * cf;
            scf[m] = t;
            mx = fmaxf(mx, t);
        }
    }
    float sum = 0.f;
#pragma unroll
    for (int m = 0; m < 5; ++m) {
        if (m < M) { scf[m] = expf(scf[m] - mx); sum += scf[m]; }
    }
    float inv = 1.0f / sum;

#pragma unroll
    for (int r = 0; r < 4; ++r) {
        int e = r * 256 + tid;
        float ctx = 0.f;
#pragma unroll
        for (int m = 0; m < 5; ++m)
            if (m < M) ctx += scf[m] * Vmem[(size_t)m * NTOK * D2 + (size_t)v * D2 + e];
        z[(size_t)v * D2 + e] += 0.1f * ctx * inv;
    }
}

// ---------------- finish: wave-shuffle reductions, 7 barriers ----------------
// grid 256 (1 token/block), block 512.
__global__ __launch_bounds__(512) void finish_kernel(float* __restrict__ z,
                                                     const float* __restrict__ sym,
                                                     const float* __restrict__ snorm,
                                                     const float* __restrict__ con,
                                                     const float* __restrict__ conT,
                                                     const float* __restrict__ symP,
                                                     float* __restrict__ conf,
                                                     float* __restrict__ symErr,
                                                     float* __restrict__ conErr) {
    int t0 = blockIdx.x, tid = threadIdx.x;
    int lane = tid & 63, w = tid >> 6;
    __shared__ __align__(16) float s_z[D2];
    __shared__ float wA[8];               // ||z||^2 partials
    __shared__ float wB[8]; __shared__ int wiB[8];   // sym argmin partials
    __shared__ float wC[8], wD[8];        // symErr, ||zs||^2 partials
    __shared__ float wE[8];               // conErr partials
    __shared__ int   s_ci[1];
    __shared__ float s_pd[512], s_pc[512];

    if (tid < 256) ((float4*)s_z)[tid] = ((const float4*)(z + (size_t)t0 * D2))[tid];
    __syncthreads();                                              // B0

    // ||z||^2
    {
        float a = s_z[tid], b = s_z[512 + tid];
        float nrm = wave_sum(a * a + b * b);
        if (lane == 0) wA[w] = nrm;
    }
    __syncthreads();                                              // B1
    float znorm = 0.f;
#pragma unroll
    for (int k = 0; k < 8; ++k) znorm += wA[k];

    // sym distance + argmin (tid = code index, 512 codes)
    {
        float dot = 0.f;
#pragma unroll
        for (int s = 0; s < 8; ++s)
            dot += symP[((size_t)s * NTOK + t0) * NSYM + tid];
        float d = (znorm + snorm[tid]) - 2.f * dot;
        int idx = tid;
        wave_argmin(d, idx);
        if (lane == 0) { wB[w] = d; wiB[w] = idx; }
    }
    __syncthreads();                                              // B2
    float dmin = wB[0]; int si = wiB[0];
#pragma unroll
    for (int k = 1; k < 8; ++k) {
        if (wB[k] < dmin || (wB[k] == dmin && wiB[k] < si)) { dmin = wB[k]; si = wiB[k]; }
    }
    if (tid == 0) conf[t0] = 1.0f / (1.0f + dmin);

    // straight-through update + symErr + ||zs||^2 (dual reduce)
    {
        const float* crow = sym + (size_t)si * D2;
        float errp = 0.f, zn2 = 0.f;
#pragma unroll
        for (int r = 0; r < 2; ++r) {
            int e = r * 512 + tid;
            float zf = s_z[e];
            float diff = crow[e] - zf;
            errp += diff * diff;
            float zn = zf + diff;
            zn2 += zn * zn;
            s_z[e] = zn;
            z[(size_t)t0 * D2 + e] = zn;
        }
        errp = wave_sum(errp);
        zn2  = wave_sum(zn2);
        if (lane == 0) { wC[w] = errp; wD[w] = zn2; }
    }
    __syncthreads();                                              // B3 (also publishes s_z)
    if (tid == 0) {
        float s = 0.f;
#pragma unroll
        for (int k = 0; k < 8; ++k) s += wC[k];
        symErr[t0] += s;
    }
    float zsnorm = 0.f;
#pragma unroll
    for (int k = 0; k < 8; ++k) zsnorm += wD[k];

    // con partial dots: 8 k-slices of 128 across all 512 threads
    {
        int c = tid & 63, sl = tid >> 6;
        float pd = 0.f, pc = 0.f;
        int kk0 = sl * 128;
#pragma unroll 4
        for (int k = kk0; k < kk0 + 128; ++k) {
            float wv = conT[(size_t)k * NCON + c];
            pd += wv * s_z[k];
            pc += wv * wv;
        }
        s_pd[tid] = pd; s_pc[tid] = pc;
    }
    __syncthreads();                                              // B4
    if (tid < 64) {
        float dot2 = 0.f, cn2 = 0.f;
#pragma unroll
        for (int i = 0; i < 8; ++i) { dot2 += s_pd[tid + 64 * i]; cn2 += s_pc[tid + 64 * i]; }
        float dc = (zsnorm + cn2) - 2.f * dot2;
        int ic = tid;
        wave_argmin(dc, ic);
        if (tid == 0) s_ci[0] = ic;
    }
    __syncthreads();                                              // B5
    int ci0 = s_ci[0];

    // conErr
    {
        const float* crow = con + (size_t)ci0 * D2;
        float p = 0.f;
#pragma unroll
        for (int r = 0; r < 2; ++r) {
            int e = r * 512 + tid;
            float diff = crow[e] - s_z[e];
            p += diff * diff;
        }
        p = wave_sum(p);
        if (lane == 0) wE[w] = p;
    }
    __syncthreads();                                              // B6
    if (tid == 0) {
        float s = 0.f;
#pragma unroll
        for (int k = 0; k < 8; ++k) s += wE[k];
        conErr[t0] += s;
    }
}

// ---------------- scatter + fused loss (last block) ----------------
__global__ __launch_bounds__(256) void scatter_kernel(const int* __restrict__ x,
                                                      const float* __restrict__ rows,
                                                      float* __restrict__ out,
                                                      const int* __restrict__ hist,
                                                      const float* __restrict__ symErr,
                                                      const float* __restrict__ conErr) {
    int tid = threadIdx.x;
    if (blockIdx.x == BS_TOT / 4) {
        __shared__ double rs[256], rc[256];
        rs[tid] = (double)hist[tid] * (double)symErr[tid];
        rc[tid] = (double)hist[tid] * (double)conErr[tid];
        __syncthreads();
        for (int off = 128; off > 0; off >>= 1) {
            if (tid < off) { rs[tid] += rs[tid + off]; rc[tid] += rc[tid + off]; }
            __syncthreads();
        }
        if (tid == 0) {
            const double denom = (double)BS_TOT * (double)D2;
            out[(size_t)BS_TOT * VOCAB]     = (float)(1.25 * rs[0] / denom);
            out[(size_t)BS_TOT * VOCAB + 1] = (float)(1.25 * rc[0] / denom);
        }
        return;
    }
    int pos = blockIdx.x * 4 + (tid >> 6);
    int lane = tid & 63;
    int v = x[pos];
    const float4* r = (const float4*)(rows + (size_t)v * VOCAB);
    ((float4*)(out + (size_t)pos * VOCAB))[lane] = r[lane];
}

// ---------------- host ----------------
extern "C" void kernel_launch(void* const* d_in, const int* in_sizes, int n_in,
                              void* d_out, int out_size, void* d_ws, size_t ws_size,
                              hipStream_t stream) {
    const int*   x     = (const int*)  d_in[0];
    const float* mag   = (const float*)d_in[1];
    const float* phase = (const float*)d_in[2];
    const float* Wr    = (const float*)d_in[3];
    const float* Wi    = (const float*)d_in[4];
    const float* qw    = (const float*)d_in[5];
    const float* qb    = (const float*)d_in[6];
    const float* kw    = (const float*)d_in[7];
    const float* kb    = (const float*)d_in[8];
    const float* vw    = (const float*)d_in[9];
    const float* vb    = (const float*)d_in[10];
    const float* dec_w = (const float*)d_in[11];
    const float* dec_b = (const float*)d_in[12];
    const float* sym   = (const float*)d_in[13];
    const float* con   = (const float*)d_in[14];
    float* out = (float*)d_out;

    // workspace layout (floats); total ~42.5 MB
    float* ws     = (float*)d_ws;
    float* bufA   = ws;                          // 256*1024
    float* bufB   = bufA + NTOK * D2;            // 256*1024
    float* Kmem   = bufB + NTOK * D2;            // 6*256*512
    float* Vmem   = Kmem + NDEPTH * NTOK * DD;   // 6*256*1024
    float* rows   = Vmem + NDEPTH * NTOK * D2;   // 256*256
    float* CW     = rows + NTOK * VOCAB;         // 1024*1024
    float* qwT    = CW + D2 * D2;                // 1024*512
    float* KVT    = qwT + D2 * DD;               // 1024*1536
    float* symT   = KVT + D2 * 1536;             // 1024*512
    float* decT   = symT + D2 * NSYM;            // 1024*256
    float* conT   = decT + D2 * VOCAB;           // 1024*64
    float* bigP   = conT + D2 * NCON;            // 2,097,152 (cellP 8x256x1024 | QP/symP/decP)
    float* kvP    = bigP + 8 * NTOK * D2;        // 4*256*1536
    float* snorm  = kvP + 4 * NTOK * 1536;       // 512
    float* conf   = snorm + NSYM;                // 256
    float* symErr = conf + NTOK;                 // 256
    float* conErr = symErr + NTOK;               // 256
    int*   hist   = (int*)(conErr + NTOK);       // 256

    float* QP   = bigP;                 // 8*256*512 = 1,048,576 floats
    float* symP = bigP + 1048576;       // 8*256*512
    float* decP = bigP;                 // 16*256*256 = 1,048,576

    dim3 tb(32, 8);
    tbatch_kernel<<<2881, tb, 0, stream>>>(qw, kw, vw, sym, dec_w, con,
                                           qwT, KVT, symT, decT, conT,
                                           symErr, conErr, hist);
    buildcw_kernel<<<dim3(16, 16), tb, 0, stream>>>(Wr, Wi, CW);
    hist_kernel<<<BS_TOT / 256, 256, 0, stream>>>(x, hist);
    symembed_kernel<<<NTOK + NSYM, 512, 0, stream>>>(mag, phase, sym, bufA, snorm);

    float* cur = bufA;
    float* oth = bufB;
    for (int d = 0; d < NDEPTH; ++d) {
        gemmT_kernel<128><<<dim3(16, 4, 8), 256, 0, stream>>>(CW, cur, bigP, D2);
        epikv_kernel<<<dim3(8, 256), 256, 0, stream>>>(
            bigP, oth, kvP, kb, vb,
            d > 0 ? Kmem + (size_t)(d - 1) * NTOK * DD : Kmem,
            d > 0 ? Vmem + (size_t)(d - 1) * NTOK * D2 : Vmem,
            d > 0 ? 1 : 0);
        { float* t = cur; cur = oth; oth = t; }
        if (d > 0) {
            gemmT_kernel<128><<<dim3(8, 4, 8), 256, 0, stream>>>(qwT, cur, QP, DD);
            attend_kernel<<<NTOK, 256, 0, stream>>>(cur, QP, qb, Kmem, Vmem, conf, d);
        }
        gemmT_kernel<128><<<dim3(8, 4, 8), 256, 0, stream>>>(symT, cur, symP, NSYM);
        finish_kernel<<<NTOK, 512, 0, stream>>>(cur, sym, snorm, con, conT, symP,
                                                conf, symErr, conErr);
        if (d < NDEPTH - 1)   // slot 5 is never read: skip dead KV work at d=5
            gemmT_kernel<256><<<dim3(24, 4, 4), 256, 0, stream>>>(KVT, cur, kvP, 1536);
    }
    for (int l = 0; l < NLOOK; ++l) {
        gemmT_kernel<128><<<dim3(16, 4, 8), 256, 0, stream>>>(CW, cur, bigP, D2);
        epikv_kernel<<<dim3(8, 256), 256, 0, stream>>>(bigP, oth, kvP, kb, vb,
                                                       Kmem, Vmem, 0);
        { float* t = cur; cur = oth; oth = t; }
    }
    gemmT_kernel<64><<<dim3(4, 4, 16), 256, 0, stream>>>(decT, cur, decP, VOCAB);
    deccomb_kernel<<<256, 256, 0, stream>>>(decP, dec_b, rows);
    scatter_kernel<<<BS_TOT / 4 + 1, 256, 0, stream>>>(x, rows, out, hist, symErr, conErr);
}